// Round 5
// baseline (5999.256 us; speedup 1.0000x reference)
//
#include <hip/hip_runtime.h>

#define B_ 64
#define S_ 512
#define I_ 512
#define H_ 1024
#define NBLK 128
#define OFF_H 33554432            // B_*S_*H_
#define OFF_C (33554432 + 65536)  // + B_*H_

typedef short bf16x8 __attribute__((ext_vector_type(8)));
typedef unsigned short u16x8 __attribute__((ext_vector_type(8)));
typedef float f32x4 __attribute__((ext_vector_type(4)));
typedef unsigned long long ull;

__device__ __forceinline__ unsigned short f2b(float f) {
  unsigned u = __float_as_uint(f);
  u += 0x7fffu + ((u >> 16) & 1u);   // RNE
  return (unsigned short)(u >> 16);
}
__device__ __forceinline__ float sigf(float x) { return 1.0f / (1.0f + __expf(-x)); }
__device__ __forceinline__ float tanh_(float x) { return 2.0f / (1.0f + __expf(-2.0f * x)) - 1.0f; }

// ---------- preamble: x -> bf16 ----------
__global__ __launch_bounds__(256) void k_cvt_x(const float* __restrict__ x,
                                               unsigned short* __restrict__ x16) {
  long long i = ((long long)blockIdx.x * 256 + threadIdx.x) * 8;
  float4 a = *(const float4*)(x + i);
  float4 b = *(const float4*)(x + i + 4);
  u16x8 o;
  o[0] = f2b(a.x); o[1] = f2b(a.y); o[2] = f2b(a.z); o[3] = f2b(a.w);
  o[4] = f2b(b.x); o[5] = f2b(b.y); o[6] = f2b(b.z); o[7] = f2b(b.w);
  *(u16x8*)(x16 + i) = o;
}

// ---------- preamble: W_x -> fragment-ordered bf16 [g][ct2][kc16][lane][8] ----------
__global__ __launch_bounds__(256) void k_wx(const float* __restrict__ Wx,
                                            unsigned short* __restrict__ wxf) {
  int gid = blockIdx.x * 256 + threadIdx.x;
  int lane = gid & 63, kc = (gid >> 6) & 15, ct = (gid >> 10) & 1, g = gid >> 11;
  int c = lane & 15, q = lane >> 4;
  int col = (ct * 2 + (c >> 3)) * H_ + g * 8 + (c & 7);  // gate-major column mapping
  int k0 = kc * 32 + q * 8;
  u16x8 o;
#pragma unroll
  for (int j = 0; j < 8; ++j) o[j] = f2b(Wx[(long long)(k0 + j) * (4 * H_) + col]);
  *(u16x8*)(wxf + (long long)gid * 8) = o;
}

// ---------- preamble: W_h -> fragment-ordered bf16 [g][ct2][kc32][lane][8] ----------
__global__ __launch_bounds__(256) void k_wh(const float* __restrict__ Wh,
                                            unsigned short* __restrict__ whf) {
  int gid = blockIdx.x * 256 + threadIdx.x;
  int lane = gid & 63, kc = (gid >> 6) & 31, ct = (gid >> 11) & 1, g = gid >> 12;
  int c = lane & 15, q = lane >> 4;
  int col = (ct * 2 + (c >> 3)) * H_ + g * 8 + (c & 7);
  int k0 = kc * 32 + q * 8;
  u16x8 o;
#pragma unroll
  for (int j = 0; j < 8; ++j) o[j] = f2b(Wh[(long long)(k0 + j) * (4 * H_) + col]);
  *(u16x8*)(whf + (long long)gid * 8) = o;
}

// ---------- persistent scan kernel: 128 blocks x 256 threads ----------
// Round-5: PRIVATE MAILBOXES x L2-ROUTED DATA (first combination of the
// two independently-proven fixes). Round-2 fixed flag hot-line queueing
// (per-consumer-wave mailbox rows: single reader per line) but kept the
// L3 data-volume wall. Round-3 fixed the data wall (strictly-gated
// NORMAL cached h loads: 16 blocks/XCD share L2 lines) but reverted to
// SHARED flags (~8 hot L3 lines polled by 128 waves each -> us-scale
// queueing on detection = the stubborn ~8us/step). This round: both.
// Consumer: minimal-VALU poll of its private 512B row, then straight-
// line bulk load (unconditional -> hv stays in VGPRs; round-4's masked
// writes demoted hv to scratch, VGPR=160 proved it) + MFMA chain.
// Producer: h agent-stores -> s_waitcnt vmcnt(0) -> posted epoch
// broadcast to 128 consumer rows (2 scattered stores/lane, off-path).
__global__ __launch_bounds__(256, 1) void k_scan(
    const unsigned short* __restrict__ x16, const unsigned short* __restrict__ wxf,
    const unsigned short* __restrict__ whf, const float* __restrict__ bias,
    unsigned short* __restrict__ hbuf, unsigned* __restrict__ mbox,
    float* __restrict__ out) {
  __shared__ unsigned short ldsWh[2 * 32 * 64 * 8];  // 64 KB, fragment order
  __shared__ unsigned short ldsWx[2 * 16 * 64 * 8];  // 32 KB, fragment order
  const int tid = threadIdx.x, g = blockIdx.x;

  for (int i = tid; i < 4096; i += 256)
    ((u16x8*)ldsWh)[i] = ((const u16x8*)(whf + (long long)g * 32768))[i];
  for (int i = tid; i < 2048; i += 256)
    ((u16x8*)ldsWx)[i] = ((const u16x8*)(wxf + (long long)g * 16384))[i];
  __syncthreads();  // the ONLY barrier; LDS is read-only afterwards

  const int wave = tid >> 6, lane = tid & 63;
  const int c = lane & 15, q = lane >> 4;
  const int rowA = wave * 16 + c;   // A-operand batch row
  const int kofs = q * 8;
  const int j = 8 * g + (c & 7);    // hidden index owned (lanes c<8)
  const float bias0 = bias[(c >> 3) * H_ + j];        // i (c<8) / f (c>=8)
  const float bias1 = bias[(2 + (c >> 3)) * H_ + j];  // g / o
  const int rowD = wave * 16 + q * 4;
  f32x4 cst = {0.f, 0.f, 0.f, 0.f};

  const unsigned short* xrow = x16 + (long long)rowA * (S_ * I_) + kofs;
  const ull* hrow = (const ull*)(hbuf + (long long)rowA * H_ + kofs);
  // private poll row for this consumer wave: mbox[g][wave][0..127]
  const unsigned* mb = mbox + (g * 4 + wave) * 128;
  // producer-side targets: lane posts this wave's epoch to consumers
  // cg = lane and cg = lane+64 (one u32 each, fire-and-forget)
  unsigned* mw0 = mbox + (lane * 4 + wave) * 128 + g;
  unsigned* mw1 = mbox + ((lane + 64) * 4 + wave) * 128 + g;

  for (int t = 0; t < S_; ++t) {
    f32x4 a0 = {bias0, bias0, bias0, bias0};
    f32x4 a1 = {bias1, bias1, bias1, bias1};

    // ---- x-part: independent of h_t; overlaps peers' h_t propagation ----
    const unsigned short* xp = xrow + t * I_;
#pragma unroll
    for (int kc = 0; kc < 16; ++kc) {
      bf16x8 av = *(const bf16x8*)(xp + kc * 32);
      bf16x8 b0 = *(const bf16x8*)(ldsWx + kc * 512 + lane * 8);
      bf16x8 b1 = *(const bf16x8*)(ldsWx + (16 + kc) * 512 + lane * 8);
      a0 = __builtin_amdgcn_mfma_f32_16x16x32_bf16(av, b0, a0, 0, 0, 0);
      a1 = __builtin_amdgcn_mfma_f32_16x16x32_bf16(av, b1, a1, 0, 0, 0);
    }

    // ---- h-part: poll private row until ALL ready, then bulk consume ----
    if (t > 0) {
      const unsigned tgt = (unsigned)t;
      // minimal-VALU spin on 8 private lines (single reader -> no queueing)
      for (;;) {
        unsigned f0 = __hip_atomic_load(mb + lane, __ATOMIC_RELAXED,
                                        __HIP_MEMORY_SCOPE_AGENT);
        unsigned f1 = __hip_atomic_load(mb + 64 + lane, __ATOMIC_RELAXED,
                                        __HIP_MEMORY_SCOPE_AGENT);
        if (__all(f0 >= tgt && f1 >= tgt)) break;
      }
      // keep the cached data loads below from hoisting above the poll
      asm volatile("" ::: "memory");

      // straight-line bulk load: unconditional -> hv lives in VGPRs
      const bf16x8* hp = (const bf16x8*)(hrow + (long long)t * 16384);
      bf16x8 hv[32];
#pragma unroll
      for (int kc = 0; kc < 32; ++kc) hv[kc] = hp[kc * 4];  // NORMAL loads: L2-shared
#pragma unroll
      for (int kc = 0; kc < 32; ++kc) {
        bf16x8 b0 = *(const bf16x8*)(ldsWh + kc * 512 + lane * 8);
        bf16x8 b1 = *(const bf16x8*)(ldsWh + (32 + kc) * 512 + lane * 8);
        a0 = __builtin_amdgcn_mfma_f32_16x16x32_bf16(hv[kc], b0, a0, 0, 0, 0);
        a1 = __builtin_amdgcn_mfma_f32_16x16x32_bf16(hv[kc], b1, a1, 0, 0, 0);
      }
    }

    // ---- elementwise LSTM update (lane c pairs with lane c+8) ----
    f32x4 h4;
#pragma unroll
    for (int r = 0; r < 4; ++r) {
      float fg = __shfl_xor(a0[r], 8, 64);  // f at lanes c<8
      float og = __shfl_xor(a1[r], 8, 64);  // o at lanes c<8
      float iv = sigf(a0[r]);
      float fv = sigf(fg);
      float gv = tanh_(a1[r]);
      float ov = sigf(og);
      float cv = fv * cst[r] + iv * gv;
      cst[r] = cv;
      h4[r] = ov * tanh_(cv);
    }

    // ---- publish h_{t+1}: agent stores (bypass own L2, land in L3) ----
    if (c < 8) {
      unsigned short* hw = hbuf + (long long)(t + 1) * (B_ * H_);
#pragma unroll
      for (int r = 0; r < 4; ++r) {
        int b = rowD + r;
        unsigned short hb = f2b(h4[r]);
        unsigned pv = (unsigned)__shfl_xor((int)hb, 1, 64) & 0xffffu;
        if ((c & 1) == 0) {
          __hip_atomic_store((unsigned*)(hw + b * H_ + j),
                             ((unsigned)hb) | (pv << 16), __ATOMIC_RELAXED,
                             __HIP_MEMORY_SCOPE_AGENT);
        }
      }
    }
    // order data -> flags: drain h stores to the coherence point, THEN
    // broadcast the epoch to all 128 consumers' private rows (posted).
    asm volatile("s_waitcnt vmcnt(0)" ::: "memory");
    {
      unsigned e = (unsigned)(t + 1);
      __hip_atomic_store(mw0, e, __ATOMIC_RELAXED, __HIP_MEMORY_SCOPE_AGENT);
      __hip_atomic_store(mw1, e, __ATOMIC_RELAXED, __HIP_MEMORY_SCOPE_AGENT);
    }

    // ---- out f32 stores AFTER publish: fully off the critical path ----
    if (c < 8) {
#pragma unroll
      for (int r = 0; r < 4; ++r) {
        int b = rowD + r;
        out[((long long)b * S_ + t) * H_ + j] = h4[r];
      }
      if (t == S_ - 1) {
#pragma unroll
        for (int r = 0; r < 4; ++r) {
          int b = rowD + r;
          out[OFF_H + b * H_ + j] = h4[r];
          out[OFF_C + b * H_ + j] = cst[r];
        }
      }
    }
  }
}

extern "C" void kernel_launch(void* const* d_in, const int* in_sizes, int n_in,
                              void* d_out, int out_size, void* d_ws, size_t ws_size,
                              hipStream_t stream) {
  const float* x = (const float*)d_in[0];
  const float* Wx = (const float*)d_in[1];
  const float* Wh = (const float*)d_in[2];
  const float* bias = (const float*)d_in[3];
  float* out = (float*)d_out;
  char* ws = (char*)d_ws;

  // ws layout (bytes):
  //   [0, 262144)               mbox u32[128 consumers][4 waves][128 producers]
  //   [262144, 67502080)        h regions, bf16 [513][64][1024] (write-once per step)
  //   [67502080, 101056512)     x16 bf16 (33.5 MB)
  //   [101056512, 105250816)    wxf fragment-ordered W_x bf16 (4 MB)
  //   [105250816, 113639424)    whf fragment-ordered W_h bf16 (8 MB)  total ~113.6 MB
  unsigned* mbox = (unsigned*)ws;
  unsigned short* hbuf = (unsigned short*)(ws + 262144);
  unsigned short* x16 = (unsigned short*)(ws + 67502080);
  unsigned short* wxf = (unsigned short*)(ws + 101056512);
  unsigned short* whf = (unsigned short*)(ws + 105250816);

  // zero ONLY the mailboxes (h regions are strictly flag-gated; no tokens)
  hipMemsetAsync(ws, 0, 262144, stream);
  hipLaunchKernelGGL(k_cvt_x, dim3(8192), dim3(256), 0, stream, x, x16);
  hipLaunchKernelGGL(k_wx, dim3(1024), dim3(256), 0, stream, Wx, wxf);
  hipLaunchKernelGGL(k_wh, dim3(2048), dim3(256), 0, stream, Wh, whf);
  hipLaunchKernelGGL(k_scan, dim3(NBLK), dim3(256), 0, stream, x16, wxf, whf, bias,
                     hbuf, mbox, out);
  (void)in_sizes; (void)n_in; (void)out_size; (void)ws_size;
}

// Round 7
// 5346.406 us; speedup vs baseline: 1.1221x; 1.1221x over previous
//
#include <hip/hip_runtime.h>

#define B_ 64
#define S_ 512
#define I_ 512
#define H_ 1024
#define NBLK 128
#define OFF_H 33554432            // B_*S_*H_
#define OFF_C (33554432 + 65536)  // + B_*H_

typedef short bf16x8 __attribute__((ext_vector_type(8)));
typedef unsigned short u16x8 __attribute__((ext_vector_type(8)));
typedef float f32x4 __attribute__((ext_vector_type(4)));
typedef unsigned long long ull;

__device__ __forceinline__ unsigned short f2b(float f) {
  unsigned u = __float_as_uint(f);
  u += 0x7fffu + ((u >> 16) & 1u);   // RNE
  return (unsigned short)(u >> 16);
}
__device__ __forceinline__ float sigf(float x) { return 1.0f / (1.0f + __expf(-x)); }
__device__ __forceinline__ float tanh_(float x) { return 2.0f / (1.0f + __expf(-2.0f * x)) - 1.0f; }

// ---------- preamble: x -> bf16 ----------
__global__ __launch_bounds__(256) void k_cvt_x(const float* __restrict__ x,
                                               unsigned short* __restrict__ x16) {
  long long i = ((long long)blockIdx.x * 256 + threadIdx.x) * 8;
  float4 a = *(const float4*)(x + i);
  float4 b = *(const float4*)(x + i + 4);
  u16x8 o;
  o[0] = f2b(a.x); o[1] = f2b(a.y); o[2] = f2b(a.z); o[3] = f2b(a.w);
  o[4] = f2b(b.x); o[5] = f2b(b.y); o[6] = f2b(b.z); o[7] = f2b(b.w);
  *(u16x8*)(x16 + i) = o;
}

// ---------- preamble: W_x -> fragment-ordered bf16 [g][ct2][kc16][lane][8] ----------
__global__ __launch_bounds__(256) void k_wx(const float* __restrict__ Wx,
                                            unsigned short* __restrict__ wxf) {
  int gid = blockIdx.x * 256 + threadIdx.x;
  int lane = gid & 63, kc = (gid >> 6) & 15, ct = (gid >> 10) & 1, g = gid >> 11;
  int c = lane & 15, q = lane >> 4;
  int col = (ct * 2 + (c >> 3)) * H_ + g * 8 + (c & 7);  // gate-major column mapping
  int k0 = kc * 32 + q * 8;
  u16x8 o;
#pragma unroll
  for (int j = 0; j < 8; ++j) o[j] = f2b(Wx[(long long)(k0 + j) * (4 * H_) + col]);
  *(u16x8*)(wxf + (long long)gid * 8) = o;
}

// ---------- preamble: W_h -> fragment-ordered bf16 [g][ct2][kc32][lane][8] ----------
__global__ __launch_bounds__(256) void k_wh(const float* __restrict__ Wh,
                                            unsigned short* __restrict__ whf) {
  int gid = blockIdx.x * 256 + threadIdx.x;
  int lane = gid & 63, kc = (gid >> 6) & 31, ct = (gid >> 11) & 1, g = gid >> 12;
  int c = lane & 15, q = lane >> 4;
  int col = (ct * 2 + (c >> 3)) * H_ + g * 8 + (c & 7);
  int k0 = kc * 32 + q * 8;
  u16x8 o;
#pragma unroll
  for (int j = 0; j < 8; ++j) o[j] = f2b(Wh[(long long)(k0 + j) * (4 * H_) + col]);
  *(u16x8*)(whf + (long long)gid * 8) = o;
}

// ---------- persistent scan kernel: 128 blocks x 256 threads ----------
// Round-6 (re-run; round-6 bench died on container infra, not the kernel):
// SHARED FLAGS (R3 producer/detect) x BULK CONSUMER (R5).
// Five-round A/B matrix: shared-flag read contention is NOT a cost
// (R5's single-reader mailboxes LOST to R3's 128-readers-per-line),
// mailbox broadcast IS a cost (~3us/step: 512 scattered agent stores/
// block/step + in-order vmcnt drain against them), and L2-routed cached
// h loads ARE a win (R1->R3). Remaining untested lever: R3's chunk-gated
// consumer serialized {poll RTT -> data RTT -> MFMA} per arrival clump
// (vmcnt is in-order -> every poll drains the prior clump's loads).
// This round: poll-until-ALL-ready with minimal VALU, then straight-line
// bulk cached loads feeding the MFMA chain (compiler pipelines with
// rolling vmcnt; unconditional loads stay in VGPRs - R4's masked writes
// demoted to scratch, R5's straight-line did not).
// Producer: h agent-stores -> s_waitcnt vmcnt(0) -> ONE flag store/wave.
// Dependency graph is per-wave-plane: consumer wave w reads h rows
// [16w,16w+16) produced only by wave w of each block, and polls exactly
// those producers' flags -> no cycle, no deadlock.
__global__ __launch_bounds__(256, 1) void k_scan(
    const unsigned short* __restrict__ x16, const unsigned short* __restrict__ wxf,
    const unsigned short* __restrict__ whf, const float* __restrict__ bias,
    unsigned short* __restrict__ hbuf, unsigned* __restrict__ flags,
    float* __restrict__ out) {
  __shared__ unsigned short ldsWh[2 * 32 * 64 * 8];  // 64 KB, fragment order
  __shared__ unsigned short ldsWx[2 * 16 * 64 * 8];  // 32 KB, fragment order
  const int tid = threadIdx.x, g = blockIdx.x;

  for (int i = tid; i < 4096; i += 256)
    ((u16x8*)ldsWh)[i] = ((const u16x8*)(whf + (long long)g * 32768))[i];
  for (int i = tid; i < 2048; i += 256)
    ((u16x8*)ldsWx)[i] = ((const u16x8*)(wxf + (long long)g * 16384))[i];
  __syncthreads();  // the ONLY barrier; LDS is read-only afterwards

  const int wave = tid >> 6, lane = tid & 63;
  const int c = lane & 15, q = lane >> 4;
  const int rowA = wave * 16 + c;   // A-operand batch row
  const int kofs = q * 8;
  const int j = 8 * g + (c & 7);    // hidden index owned (lanes c<8)
  const float bias0 = bias[(c >> 3) * H_ + j];        // i (c<8) / f (c>=8)
  const float bias1 = bias[(2 + (c >> 3)) * H_ + j];  // g / o
  const int rowD = wave * 16 + q * 4;
  f32x4 cst = {0.f, 0.f, 0.f, 0.f};

  const unsigned short* xrow = x16 + (long long)rowA * (S_ * I_) + kofs;
  const ull* hrow = (const ull*)(hbuf + (long long)rowA * H_ + kofs);
  const unsigned* fl = flags + wave * 128;  // this wave-plane's flag row

  for (int t = 0; t < S_; ++t) {
    f32x4 a0 = {bias0, bias0, bias0, bias0};
    f32x4 a1 = {bias1, bias1, bias1, bias1};

    // ---- x-part: independent of h_t; overlaps peers' h_t propagation ----
    const unsigned short* xp = xrow + t * I_;
#pragma unroll
    for (int kc = 0; kc < 16; ++kc) {
      bf16x8 av = *(const bf16x8*)(xp + kc * 32);
      bf16x8 b0 = *(const bf16x8*)(ldsWx + kc * 512 + lane * 8);
      bf16x8 b1 = *(const bf16x8*)(ldsWx + (16 + kc) * 512 + lane * 8);
      a0 = __builtin_amdgcn_mfma_f32_16x16x32_bf16(av, b0, a0, 0, 0, 0);
      a1 = __builtin_amdgcn_mfma_f32_16x16x32_bf16(av, b1, a1, 0, 0, 0);
    }

    // ---- h-part: poll shared flags until ALL ready, then bulk consume ----
    if (t > 0) {
      const unsigned tgt = (unsigned)t;
      // minimal-VALU spin: 2 agent loads/lane over the wave-plane's 128
      // flags; L3 serves many readers of one line fine (R5 falsified the
      // contention theory). No data loads inside -> no vmcnt coupling.
      for (;;) {
        unsigned f0 = __hip_atomic_load(fl + lane, __ATOMIC_RELAXED,
                                        __HIP_MEMORY_SCOPE_AGENT);
        unsigned f1 = __hip_atomic_load(fl + 64 + lane, __ATOMIC_RELAXED,
                                        __HIP_MEMORY_SCOPE_AGENT);
        if (__all(f0 >= tgt && f1 >= tgt)) break;
      }
      // keep the cached data loads below from hoisting above the poll
      asm volatile("" ::: "memory");

      // straight-line bulk load: unconditional -> registers; compiler
      // pipelines these into the MFMA chain with rolling waitcnt.
      const bf16x8* hp = (const bf16x8*)(hrow + (long long)t * 16384);
      bf16x8 hv[32];
#pragma unroll
      for (int kc = 0; kc < 32; ++kc) hv[kc] = hp[kc * 4];  // NORMAL loads: L2-shared
#pragma unroll
      for (int kc = 0; kc < 32; ++kc) {
        bf16x8 b0 = *(const bf16x8*)(ldsWh + kc * 512 + lane * 8);
        bf16x8 b1 = *(const bf16x8*)(ldsWh + (32 + kc) * 512 + lane * 8);
        a0 = __builtin_amdgcn_mfma_f32_16x16x32_bf16(hv[kc], b0, a0, 0, 0, 0);
        a1 = __builtin_amdgcn_mfma_f32_16x16x32_bf16(hv[kc], b1, a1, 0, 0, 0);
      }
    }

    // ---- elementwise LSTM update (lane c pairs with lane c+8) ----
    f32x4 h4;
#pragma unroll
    for (int r = 0; r < 4; ++r) {
      float fg = __shfl_xor(a0[r], 8, 64);  // f at lanes c<8
      float og = __shfl_xor(a1[r], 8, 64);  // o at lanes c<8
      float iv = sigf(a0[r]);
      float fv = sigf(fg);
      float gv = tanh_(a1[r]);
      float ov = sigf(og);
      float cv = fv * cst[r] + iv * gv;
      cst[r] = cv;
      h4[r] = ov * tanh_(cv);
    }

    // ---- publish h_{t+1}: agent stores (bypass own L2, land in L3) ----
    if (c < 8) {
      unsigned short* hw = hbuf + (long long)(t + 1) * (B_ * H_);
#pragma unroll
      for (int r = 0; r < 4; ++r) {
        int b = rowD + r;
        unsigned short hb = f2b(h4[r]);
        unsigned pv = (unsigned)__shfl_xor((int)hb, 1, 64) & 0xffffu;
        if ((c & 1) == 0) {
          __hip_atomic_store((unsigned*)(hw + b * H_ + j),
                             ((unsigned)hb) | (pv << 16), __ATOMIC_RELAXED,
                             __HIP_MEMORY_SCOPE_AGENT);
        }
      }
    }
    // order data -> flag: drain h stores to the coherence point, THEN
    // publish ONE per-wave epoch flag (cheapest proven publish path).
    asm volatile("s_waitcnt vmcnt(0)" ::: "memory");
    if (lane == 0)
      __hip_atomic_store((unsigned*)(flags + wave * 128 + g), (unsigned)(t + 1),
                         __ATOMIC_RELAXED, __HIP_MEMORY_SCOPE_AGENT);

    // ---- out f32 stores AFTER publish: fully off the critical path ----
    if (c < 8) {
#pragma unroll
      for (int r = 0; r < 4; ++r) {
        int b = rowD + r;
        out[((long long)b * S_ + t) * H_ + j] = h4[r];
      }
      if (t == S_ - 1) {
#pragma unroll
        for (int r = 0; r < 4; ++r) {
          int b = rowD + r;
          out[OFF_H + b * H_ + j] = h4[r];
          out[OFF_C + b * H_ + j] = cst[r];
        }
      }
    }
  }
}

extern "C" void kernel_launch(void* const* d_in, const int* in_sizes, int n_in,
                              void* d_out, int out_size, void* d_ws, size_t ws_size,
                              hipStream_t stream) {
  const float* x = (const float*)d_in[0];
  const float* Wx = (const float*)d_in[1];
  const float* Wh = (const float*)d_in[2];
  const float* bias = (const float*)d_in[3];
  float* out = (float*)d_out;
  char* ws = (char*)d_ws;

  // ws layout (bytes):
  //   [0, 2048)                 flags u32[4 waves][128 producers]
  //   [4096, 67244032)          h regions, bf16 [513][64][1024] (write-once per step)
  //   [67244032, 100798464)     x16 bf16 (33.5 MB)
  //   [100798464, 104992768)    wxf fragment-ordered W_x bf16 (4 MB)
  //   [104992768, 113381376)    whf fragment-ordered W_h bf16 (8 MB)  total ~113.4 MB
  unsigned* flags = (unsigned*)ws;
  unsigned short* hbuf = (unsigned short*)(ws + 4096);
  unsigned short* x16 = (unsigned short*)(ws + 67244032);
  unsigned short* wxf = (unsigned short*)(ws + 100798464);
  unsigned short* whf = (unsigned short*)(ws + 104992768);

  // zero ONLY the flags (h regions are strictly flag-gated; no tokens)
  hipMemsetAsync(ws, 0, 4096, stream);
  hipLaunchKernelGGL(k_cvt_x, dim3(8192), dim3(256), 0, stream, x, x16);
  hipLaunchKernelGGL(k_wx, dim3(1024), dim3(256), 0, stream, Wx, wxf);
  hipLaunchKernelGGL(k_wh, dim3(2048), dim3(256), 0, stream, Wh, whf);
  hipLaunchKernelGGL(k_scan, dim3(NBLK), dim3(256), 0, stream, x16, wxf, whf, bias,
                     hbuf, flags, out);
  (void)in_sizes; (void)n_in; (void)out_size; (void)ws_size;
}

// Round 8
// 4785.809 us; speedup vs baseline: 1.2536x; 1.1171x over previous
//
#include <hip/hip_runtime.h>

#define B_ 64
#define S_ 512
#define I_ 512
#define H_ 1024
#define NBLK 128          // scan blocks
#define NBLK_TOT 256      // + 128 ballast blocks (DPM clock-keeper)
#define NVEC 2097152      // x16 bytes / 16 = (B_*S_*I_*2)/16, power of 2
#define OFF_H 33554432            // B_*S_*H_
#define OFF_C (33554432 + 65536)  // + B_*H_

typedef short bf16x8 __attribute__((ext_vector_type(8)));
typedef unsigned short u16x8 __attribute__((ext_vector_type(8)));
typedef float f32x4 __attribute__((ext_vector_type(4)));
typedef unsigned long long ull;

__device__ __forceinline__ unsigned short f2b(float f) {
  unsigned u = __float_as_uint(f);
  u += 0x7fffu + ((u >> 16) & 1u);   // RNE
  return (unsigned short)(u >> 16);
}
__device__ __forceinline__ float sigf(float x) { return 1.0f / (1.0f + __expf(-x)); }
__device__ __forceinline__ float tanh_(float x) { return 2.0f / (1.0f + __expf(-2.0f * x)) - 1.0f; }

// ---------- preamble: x -> bf16 ----------
__global__ __launch_bounds__(256) void k_cvt_x(const float* __restrict__ x,
                                               unsigned short* __restrict__ x16) {
  long long i = ((long long)blockIdx.x * 256 + threadIdx.x) * 8;
  float4 a = *(const float4*)(x + i);
  float4 b = *(const float4*)(x + i + 4);
  u16x8 o;
  o[0] = f2b(a.x); o[1] = f2b(a.y); o[2] = f2b(a.z); o[3] = f2b(a.w);
  o[4] = f2b(b.x); o[5] = f2b(b.y); o[6] = f2b(b.z); o[7] = f2b(b.w);
  *(u16x8*)(x16 + i) = o;
}

// ---------- preamble: W_x -> fragment-ordered bf16 [g][ct2][kc16][lane][8] ----------
__global__ __launch_bounds__(256) void k_wx(const float* __restrict__ Wx,
                                            unsigned short* __restrict__ wxf) {
  int gid = blockIdx.x * 256 + threadIdx.x;
  int lane = gid & 63, kc = (gid >> 6) & 15, ct = (gid >> 10) & 1, g = gid >> 11;
  int c = lane & 15, q = lane >> 4;
  int col = (ct * 2 + (c >> 3)) * H_ + g * 8 + (c & 7);  // gate-major column mapping
  int k0 = kc * 32 + q * 8;
  u16x8 o;
#pragma unroll
  for (int j = 0; j < 8; ++j) o[j] = f2b(Wx[(long long)(k0 + j) * (4 * H_) + col]);
  *(u16x8*)(wxf + (long long)gid * 8) = o;
}

// ---------- preamble: W_h -> fragment-ordered bf16 [g][ct2][kc32][lane][8] ----------
__global__ __launch_bounds__(256) void k_wh(const float* __restrict__ Wh,
                                            unsigned short* __restrict__ whf) {
  int gid = blockIdx.x * 256 + threadIdx.x;
  int lane = gid & 63, kc = (gid >> 6) & 31, ct = (gid >> 11) & 1, g = gid >> 12;
  int c = lane & 15, q = lane >> 4;
  int col = (ct * 2 + (c >> 3)) * H_ + g * 8 + (c & 7);
  int k0 = kc * 32 + q * 8;
  u16x8 o;
#pragma unroll
  for (int j = 0; j < 8; ++j) o[j] = f2b(Wh[(long long)(k0 + j) * (4 * H_) + col]);
  *(u16x8*)(whf + (long long)gid * 8) = o;
}

// ---------- persistent scan kernel: 256 blocks x 256 threads ----------
// Round-8: R3 SCAN (verbatim, proven 4203us) + 128 BALLAST BLOCKS.
// Theory: every protocol variant (R0-R7) lands at 8-11us/step, 3-4x the
// hop arithmetic from full-clock latencies; all run the chip at <6.5%
// occupancy / <2% HBM -> DPM parks FCLK/MCLK (fabric/L3 clocks = our
// critical path). Ballast blocks stream-read the L3-resident x16 buffer
// to keep the uncore busy, and exit when scan block (g-128) finishes
// (throttled flag check every 4th iteration). Single variable vs R3.
__global__ __launch_bounds__(256, 1) void k_scan(
    const unsigned short* __restrict__ x16, const unsigned short* __restrict__ wxf,
    const unsigned short* __restrict__ whf, const float* __restrict__ bias,
    unsigned short* __restrict__ hbuf, unsigned* __restrict__ flags,
    float* __restrict__ out) {
  __shared__ unsigned short ldsWh[2 * 32 * 64 * 8];  // 64 KB, fragment order
  __shared__ unsigned short ldsWx[2 * 16 * 64 * 8];  // 32 KB, fragment order
  const int tid = threadIdx.x, g = blockIdx.x;

  // ---- ballast blocks: fabric/L3 traffic to hold DPM clock states ----
  if (g >= NBLK) {
    const int bg = g - NBLK;
    const f32x4* src = (const f32x4*)x16;   // 33.5 MB, L3-resident
    f32x4 acc = {0.f, 0.f, 0.f, 0.f};
    unsigned i0 = (unsigned)bg * 4096u;
    unsigned it = 0;
    for (;;) {
      f32x4 s = {0.f, 0.f, 0.f, 0.f};
#pragma unroll
      for (int u = 0; u < 16; ++u)
        s += src[(i0 + u * 256u + (unsigned)tid) & (NVEC - 1u)];
      acc += s;
      i0 += 4096u;
      if ((++it & 3u) == 0u) {   // throttled exit check (~2% added poll load)
        unsigned f = __hip_atomic_load(flags + bg, __ATOMIC_RELAXED,
                                       __HIP_MEMORY_SCOPE_AGENT);
        if (f >= (unsigned)S_) break;
      }
    }
    // keep acc live (workspace scratch in [2048,4096), never read back)
    *(volatile float*)((char*)flags + 2048 + 4 * bg) =
        acc[0] + acc[1] + acc[2] + acc[3];
    return;
  }

  for (int i = tid; i < 4096; i += 256)
    ((u16x8*)ldsWh)[i] = ((const u16x8*)(whf + (long long)g * 32768))[i];
  for (int i = tid; i < 2048; i += 256)
    ((u16x8*)ldsWx)[i] = ((const u16x8*)(wxf + (long long)g * 16384))[i];
  __syncthreads();  // the ONLY barrier; LDS is read-only afterwards

  const int wave = tid >> 6, lane = tid & 63;
  const int c = lane & 15, q = lane >> 4;
  const int rowA = wave * 16 + c;   // A-operand batch row
  const int kofs = q * 8;
  const int j = 8 * g + (c & 7);    // hidden index owned (lanes c<8)
  const float bias0 = bias[(c >> 3) * H_ + j];        // i (c<8) / f (c>=8)
  const float bias1 = bias[(2 + (c >> 3)) * H_ + j];  // g / o
  const int rowD = wave * 16 + q * 4;
  f32x4 cst = {0.f, 0.f, 0.f, 0.f};

  const unsigned short* xrow = x16 + (long long)rowA * (S_ * I_) + kofs;
  const ull* hrow = (const ull*)(hbuf + (long long)rowA * H_ + kofs);
  const unsigned* fl = flags + wave * 128;  // this wave-plane's flag row

  for (int t = 0; t < S_; ++t) {
    f32x4 a0 = {bias0, bias0, bias0, bias0};
    f32x4 a1 = {bias1, bias1, bias1, bias1};

    // ---- x-part: independent of h_t; overlaps peers' h_t propagation ----
    const unsigned short* xp = xrow + t * I_;
#pragma unroll
    for (int kc = 0; kc < 16; ++kc) {
      bf16x8 av = *(const bf16x8*)(xp + kc * 32);
      bf16x8 b0 = *(const bf16x8*)(ldsWx + kc * 512 + lane * 8);
      bf16x8 b1 = *(const bf16x8*)(ldsWx + (16 + kc) * 512 + lane * 8);
      a0 = __builtin_amdgcn_mfma_f32_16x16x32_bf16(av, b0, a0, 0, 0, 0);
      a1 = __builtin_amdgcn_mfma_f32_16x16x32_bf16(av, b1, a1, 0, 0, 0);
    }

    // ---- h-part: strictly flag-gated, chunk-incremental consumption ----
    if (t > 0) {
      const ull* hq = hrow + (long long)t * 16384;  // write-once region for h_t
      unsigned done = 0u;
      const unsigned tgt = (unsigned)t;

      while (done != 0xffffffffu) {
        // poll agent-scope flags (always fresh from L3)
        unsigned f0 = __hip_atomic_load(fl + lane, __ATOMIC_RELAXED,
                                        __HIP_MEMORY_SCOPE_AGENT);
        unsigned f1 = __hip_atomic_load(fl + 64 + lane, __ATOMIC_RELAXED,
                                        __HIP_MEMORY_SCOPE_AGENT);
        ull m0 = __ballot(f0 >= tgt);   // bit L = producer L ready
        ull m1 = __ballot(f1 >= tgt);   // bit L = producer 64+L ready
        m0 &= (m0 >> 1) & (m0 >> 2) & (m0 >> 3);  // chunk ready = its 4 producers done
        m1 &= (m1 >> 1) & (m1 >> 2) & (m1 >> 3);
        unsigned hint = 0;
#pragma unroll
        for (int i = 0; i < 16; ++i) {
          hint |= (unsigned)((m0 >> (4 * i)) & 1ull) << i;
          hint |= (unsigned)((m1 >> (4 * i)) & 1ull) << (16 + i);
        }
        unsigned todo = hint & ~done;
        if (todo) {
          // keep the cached loads below from hoisting above the flag poll
          asm volatile("" ::: "memory");
          ull hlo[32], hhi[32];
#pragma unroll
          for (int kc = 0; kc < 32; ++kc) {
            if (todo & (1u << kc)) {
              hlo[kc] = hq[kc * 8];       // NORMAL load: L2-shared across XCD
              hhi[kc] = hq[kc * 8 + 1];
            }
          }
#pragma unroll
          for (int kc = 0; kc < 32; ++kc) {
            if (todo & (1u << kc)) {
              union { ull qw[2]; bf16x8 v; } u;
              u.qw[0] = hlo[kc]; u.qw[1] = hhi[kc];
              bf16x8 av = u.v;
              bf16x8 b0 = *(const bf16x8*)(ldsWh + kc * 512 + lane * 8);
              bf16x8 b1 = *(const bf16x8*)(ldsWh + (32 + kc) * 512 + lane * 8);
              a0 = __builtin_amdgcn_mfma_f32_16x16x32_bf16(av, b0, a0, 0, 0, 0);
              a1 = __builtin_amdgcn_mfma_f32_16x16x32_bf16(av, b1, a1, 0, 0, 0);
            }
          }
          done |= todo;
        }
      }
    }

    // ---- elementwise LSTM update (lane c pairs with lane c+8) ----
    f32x4 h4;
#pragma unroll
    for (int r = 0; r < 4; ++r) {
      float fg = __shfl_xor(a0[r], 8, 64);  // f at lanes c<8
      float og = __shfl_xor(a1[r], 8, 64);  // o at lanes c<8
      float iv = sigf(a0[r]);
      float fv = sigf(fg);
      float gv = tanh_(a1[r]);
      float ov = sigf(og);
      float cv = fv * cst[r] + iv * gv;
      cst[r] = cv;
      h4[r] = ov * tanh_(cv);
    }

    // ---- publish h_{t+1}: agent stores (bypass own L2, land in L3) ----
    if (c < 8) {
      unsigned short* hw = hbuf + (long long)(t + 1) * (B_ * H_);
#pragma unroll
      for (int r = 0; r < 4; ++r) {
        int b = rowD + r;
        unsigned short hb = f2b(h4[r]);
        unsigned pv = (unsigned)__shfl_xor((int)hb, 1, 64) & 0xffffu;
        if ((c & 1) == 0) {
          __hip_atomic_store((unsigned*)(hw + b * H_ + j),
                             ((unsigned)hb) | (pv << 16), __ATOMIC_RELAXED,
                             __HIP_MEMORY_SCOPE_AGENT);
        }
      }
    }
    // order data -> flag: wait for the h stores to reach the coherence
    // point, THEN publish the per-wave epoch flag (consumers gate on it).
    asm volatile("s_waitcnt vmcnt(0)" ::: "memory");
    if (lane == 0)
      __hip_atomic_store((unsigned*)(flags + wave * 128 + g), (unsigned)(t + 1),
                         __ATOMIC_RELAXED, __HIP_MEMORY_SCOPE_AGENT);

    // ---- out f32 stores AFTER publish: fully off the critical path ----
    if (c < 8) {
#pragma unroll
      for (int r = 0; r < 4; ++r) {
        int b = rowD + r;
        out[((long long)b * S_ + t) * H_ + j] = h4[r];
      }
      if (t == S_ - 1) {
#pragma unroll
        for (int r = 0; r < 4; ++r) {
          int b = rowD + r;
          out[OFF_H + b * H_ + j] = h4[r];
          out[OFF_C + b * H_ + j] = cst[r];
        }
      }
    }
  }
}

extern "C" void kernel_launch(void* const* d_in, const int* in_sizes, int n_in,
                              void* d_out, int out_size, void* d_ws, size_t ws_size,
                              hipStream_t stream) {
  const float* x = (const float*)d_in[0];
  const float* Wx = (const float*)d_in[1];
  const float* Wh = (const float*)d_in[2];
  const float* bias = (const float*)d_in[3];
  float* out = (float*)d_out;
  char* ws = (char*)d_ws;

  // ws layout (bytes):
  //   [0, 2048)                 flags u32[4 waves][128 producers]
  //   [2048, 4096)              ballast scratch (liveness sink)
  //   [4096, 67244032)          h regions, bf16 [513][64][1024] (write-once per step)
  //   [67244032, 100798464)     x16 bf16 (33.5 MB)
  //   [100798464, 104992768)    wxf fragment-ordered W_x bf16 (4 MB)
  //   [104992768, 113381376)    whf fragment-ordered W_h bf16 (8 MB)  total ~113.4 MB
  unsigned* flags = (unsigned*)ws;
  unsigned short* hbuf = (unsigned short*)(ws + 4096);
  unsigned short* x16 = (unsigned short*)(ws + 67244032);
  unsigned short* wxf = (unsigned short*)(ws + 100798464);
  unsigned short* whf = (unsigned short*)(ws + 104992768);

  // zero ONLY the flags (+scratch); h regions are strictly flag-gated
  hipMemsetAsync(ws, 0, 4096, stream);
  hipLaunchKernelGGL(k_cvt_x, dim3(8192), dim3(256), 0, stream, x, x16);
  hipLaunchKernelGGL(k_wx, dim3(1024), dim3(256), 0, stream, Wx, wxf);
  hipLaunchKernelGGL(k_wh, dim3(2048), dim3(256), 0, stream, Wh, whf);
  hipLaunchKernelGGL(k_scan, dim3(NBLK_TOT), dim3(256), 0, stream, x16, wxf, whf, bias,
                     hbuf, flags, out);
  (void)in_sizes; (void)n_in; (void)out_size; (void)ws_size;
}